// Round 5
// baseline (323.095 us; speedup 1.0000x reference)
//
#include <hip/hip_runtime.h>

typedef unsigned short ushort_t;
typedef __bf16 bf16x8 __attribute__((ext_vector_type(8)));
typedef __bf16 bf16x4 __attribute__((ext_vector_type(4)));
typedef float f32x4 __attribute__((ext_vector_type(4)));
typedef short short4v __attribute__((ext_vector_type(4)));
typedef int i32x2 __attribute__((ext_vector_type(2)));

#define NTOK 98
#define CDIM 128
#define LD   136            // LDS row stride elems: 272B = 17 x 16B slots (16B-aligned rows for b128)
#define SM_TOTAL 126208     // xb 30464 + Q 30464 + K 30464 + Vt 34816
#define QSCALE 0.2550181952219662f   // hd^-0.5 * log2(e)
#define LOG2E  1.4426950408889634f

#if defined(__has_builtin)
#if __has_builtin(__builtin_amdgcn_exp2f)
#define EXP2F(x) __builtin_amdgcn_exp2f(x)
#else
#define EXP2F(x) exp2f(x)
#endif
#if __has_builtin(__builtin_amdgcn_rcpf)
#define RCPF(x) __builtin_amdgcn_rcpf(x)
#else
#define RCPF(x) (1.f / (x))
#endif
#else
#define EXP2F(x) exp2f(x)
#define RCPF(x) (1.f / (x))
#endif

__device__ __forceinline__ f32x4 mfma16(bf16x4 a, bf16x4 b, f32x4 c) {
#if defined(__has_builtin) && __has_builtin(__builtin_amdgcn_mfma_f32_16x16x16bf16_1k)
  return __builtin_amdgcn_mfma_f32_16x16x16bf16_1k(__builtin_bit_cast(short4v, a),
                                                   __builtin_bit_cast(short4v, b), c, 0, 0, 0);
#elif defined(__has_builtin) && __has_builtin(__builtin_amdgcn_mfma_f32_16x16x16_bf16)
  return __builtin_amdgcn_mfma_f32_16x16x16_bf16(a, b, c, 0, 0, 0);
#else
  f32x4 d;
  i32x2 ai = __builtin_bit_cast(i32x2, a), bi = __builtin_bit_cast(i32x2, b);
  asm volatile("v_mfma_f32_16x16x16_bf16 %0, %1, %2, %3"
               : "=&v"(d) : "v"(ai), "v"(bi), "v"(c));
  return d;
#endif
}

// ---------------- precompute: bf16 weight fragments + fused (bias+mask)*log2e table [q][k] ----------------
__global__ void precompute_k(const float* __restrict__ qkv_w, const float* __restrict__ proj_w,
                             const float* __restrict__ bias_table, const int* __restrict__ rel_index,
                             const float* __restrict__ mask,
                             __bf16* __restrict__ wqkv, __bf16* __restrict__ wproj,
                             float* __restrict__ comb) {
  int t = blockIdx.x * blockDim.x + threadIdx.x;
  int stride = gridDim.x * blockDim.x;
  // qkv_w (128x384) -> [nt(24)][kk(4)][lane(64)][j(8)] ; elem = W[kk*32+(lane>>4)*8+j][nt*16+(lane&15)]
  for (int g = t; g < 24 * 4 * 64; g += stride) {
    int nt = g >> 8, kk = (g >> 6) & 3, lane = g & 63;
    int n = nt * 16 + (lane & 15);
    int k0 = kk * 32 + (lane >> 4) * 8;
    __bf16* dst = wqkv + g * 8;
#pragma unroll
    for (int j = 0; j < 8; ++j) dst[j] = (__bf16)qkv_w[(k0 + j) * 384 + n];
  }
  // proj_w (128x128) -> [nt(8)][kk(4)][lane][j]
  for (int g = t; g < 8 * 4 * 64; g += stride) {
    int nt = g >> 8, kk = (g >> 6) & 3, lane = g & 63;
    int n = nt * 16 + (lane & 15);
    int k0 = kk * 32 + (lane >> 4) * 8;
    __bf16* dst = wproj + g * 8;
#pragma unroll
    for (int j = 0; j < 8; ++j) dst[j] = (__bf16)proj_w[(k0 + j) * 128 + n];
  }
  // comb[h][wm][i=query(112)][j=key(112)] = (j>=98) ? -1e30 : (i>=98) ? 0 : (bias+mask)*log2e
  for (int e = t; e < 4 * 64 * 112 * 112; e += stride) {
    int j  = e % 112;
    int i  = (e / 112) % 112;
    int hw = e / (112 * 112);
    int wm = hw & 63, h = hw >> 6;
    float v;
    if (j >= NTOK) v = -1e30f;
    else if (i >= NTOK) v = 0.f;
    else v = (bias_table[rel_index[i * NTOK + j] * 4 + h] + mask[wm * (NTOK * NTOK) + i * NTOK + j]) * LOG2E;
    comb[e] = v;
  }
}

// ---------------- fused window attention: one block (1024 thr = 16 waves) per window ----------------
__launch_bounds__(1024)
__global__ void wattn_k(const float* __restrict__ x,
                        const float* __restrict__ qkv_b, const float* __restrict__ proj_b,
                        const __bf16* __restrict__ wqkv, const __bf16* __restrict__ wproj,
                        const float* __restrict__ comb, float* __restrict__ out) {
  extern __shared__ char smem[];
  // 0      .. 30464  : xb [112][LD]  (bf16 x-tile)
  // 30464  .. 60928  : Q  [112][LD]  (pre-scaled by QSCALE); aliased as O in phase 2/3
  // 60928  .. 91392  : K  [112][LD]
  // 91392  .. 126208 : Vt [128][LD]  (V transposed: Vt[channel][token])
  __bf16* const xb = (__bf16*)smem;
  __bf16* const Q  = (__bf16*)(smem + 30464);
  __bf16* const Kl = (__bf16*)(smem + 60928);
  __bf16* const Vt = (__bf16*)(smem + 91392);

  const int b    = blockIdx.x;
  const int tid  = threadIdx.x;
  const int w    = tid >> 6;
  const int lane = tid & 63;
  const int l15  = lane & 15;
  const int l4   = lane >> 4;

  // ---- stage x -> bf16 LDS (zero rows 98..111) ----
  const float* xw = x + (size_t)b * (NTOK * CDIM);
  for (int f = tid; f < NTOK * 32; f += 1024) {
    int i = f >> 5, c4 = (f & 31) << 2;
    float4 v = *(const float4*)(xw + i * CDIM + c4);
    bf16x4 o; o[0] = (__bf16)v.x; o[1] = (__bf16)v.y; o[2] = (__bf16)v.z; o[3] = (__bf16)v.w;
    *(bf16x4*)(xb + i * LD + c4) = o;
  }
  {
    bf16x4 z = {(__bf16)0.f, (__bf16)0.f, (__bf16)0.f, (__bf16)0.f};
    for (int f = tid; f < 14 * 32; f += 1024) {
      int i = NTOK + (f >> 5), c4 = (f & 31) << 2;
      *(bf16x4*)(xb + i * LD + c4) = z;
    }
  }
  __syncthreads();

  // ---- phase 1: QKV = xb @ wqkv ; 84 tile-pairs (shared A-fragments) ----
  {
    int mt = w % 7, nt2 = w / 7;
    for (int pt = w; pt < 84; pt += 16) {
      const int mb = mt << 4;
      const int ntA = nt2 << 1;
      f32x4 accA = {0.f, 0.f, 0.f, 0.f};
      f32x4 accB = {0.f, 0.f, 0.f, 0.f};
#pragma unroll
      for (int kk = 0; kk < 4; ++kk) {
        bf16x8 a  = *(const bf16x8*)(xb + (mb + l15) * LD + kk * 32 + l4 * 8);
        bf16x8 b0 = *(const bf16x8*)(wqkv + (((ntA << 2) + kk) * 64 + lane) * 8);
        bf16x8 b1 = *(const bf16x8*)(wqkv + ((((ntA + 1) << 2) + kk) * 64 + lane) * 8);
        accA = __builtin_amdgcn_mfma_f32_16x16x32_bf16(a, b0, accA, 0, 0, 0);
        accB = __builtin_amdgcn_mfma_f32_16x16x32_bf16(a, b1, accB, 0, 0, 0);
      }
      const int r0 = mb + (l4 << 2);
#pragma unroll
      for (int u = 0; u < 2; ++u) {
        f32x4 acc = u ? accB : accA;
        int nt = ntA + u;
        int n = (nt << 4) + l15;
        float bias = qkv_b[n];
        if (nt2 < 4) {                 // Q (pre-scaled)
#pragma unroll
          for (int j = 0; j < 4; ++j)
            Q[(r0 + j) * LD + n] = (__bf16)((acc[j] + bias) * QSCALE);
        } else if (nt2 < 8) {          // K
          int c = n - 128;
#pragma unroll
          for (int j = 0; j < 4; ++j)
            Kl[(r0 + j) * LD + c] = (__bf16)(acc[j] + bias);
        } else {                       // V -> transposed (4 consecutive tokens per lane)
          int c = n - 256;
          bf16x4 o; o[0] = (__bf16)(acc[0] + bias); o[1] = (__bf16)(acc[1] + bias);
                    o[2] = (__bf16)(acc[2] + bias); o[3] = (__bf16)(acc[3] + bias);
          *(bf16x4*)(Vt + c * LD + r0) = o;
        }
      }
      mt += 2; nt2 += 2;
      if (mt >= 7) { mt -= 7; ++nt2; }
    }
  }
  __syncthreads();

  // ---- phase 2: wave (m, hg) owns query m-tile, heads hg*2, hg*2+1 ----
  // Swapped QK^T: S^T = mfma(A=K, B=Q) -> lane holds P[query=l15][keys g*4+j] per key-tile:
  // directly the A-fragment of 16x16x16 PV MFMA. No LDS P, no cross-lane rearrange.
  if (w < 14) {
    const int m  = w % 7;
    const int hg = w / 7;
    const int mb = m << 4;
    const int qrow = mb + l15;          // this lane's query row (softmax owner)
#pragma unroll 1
    for (int h2 = 0; h2 < 2; ++h2) {
      const int h = hg * 2 + h2;
      const float* combw = comb + ((size_t)(h * 64 + (b & 63))) * (112 * 112) + (size_t)qrow * 112;
      bf16x8 bq = *(const bf16x8*)(Q + qrow * LD + h * 32 + l4 * 8);
      f32x4 s[7];
#pragma unroll
      for (int nt = 0; nt < 7; ++nt) {
        f32x4 c4 = *(const f32x4*)(combw + (nt << 4) + (l4 << 2));
        bf16x8 ak = *(const bf16x8*)(Kl + ((nt << 4) + l15) * LD + h * 32 + l4 * 8);
        s[nt] = __builtin_amdgcn_mfma_f32_16x16x32_bf16(ak, bq, c4, 0, 0, 0);
      }
      // unnormalized softmax, lane-local row sum (query = l15)
      float rsum = 0.f;
      bf16x4 pw[7];
#pragma unroll
      for (int nt = 0; nt < 7; ++nt) {
#pragma unroll
        for (int j = 0; j < 4; ++j) {
          float p = EXP2F(s[nt][j]);
          s[nt][j] = p;
          rsum += p;
        }
        pw[nt][0] = (__bf16)s[nt][0]; pw[nt][1] = (__bf16)s[nt][1];
        pw[nt][2] = (__bf16)s[nt][2]; pw[nt][3] = (__bf16)s[nt][3];
      }
      rsum += __shfl_xor(rsum, 16, 64);
      rsum += __shfl_xor(rsum, 32, 64);
      float inv = RCPF(rsum);
      // broadcast inv to C-layout rows: lane needs inv of queries l4*4+j
      float invq[4];
#pragma unroll
      for (int j = 0; j < 4; ++j) invq[j] = __shfl(inv, (l4 << 2) + j, 64);
      // PV: O_tile(16x32) = P(16x112) @ V(112x32) via 7 x mfma 16x16x16 per 16-col tile
#pragma unroll
      for (int no = 0; no < 2; ++no) {
        f32x4 acc = {0.f, 0.f, 0.f, 0.f};
#pragma unroll
        for (int nt = 0; nt < 7; ++nt) {
          bf16x4 bv = *(const bf16x4*)(Vt + (h * 32 + (no << 4) + l15) * LD + (nt << 4) + (l4 << 2));
          acc = mfma16(pw[nt], bv, acc);
        }
        int c = h * 32 + (no << 4) + l15;
#pragma unroll
        for (int j = 0; j < 4; ++j)
          Q[(mb + (l4 << 2) + j) * LD + c] = (__bf16)(acc[j] * invq[j]);
      }
    }
  }
  __syncthreads();

  // ---- phase 3: out = O @ proj_w + proj_b (O in Q buffer); 28 tile-pairs ----
  {
    float* outw = out + (size_t)b * (NTOK * CDIM);
    int mt = w % 7, nt2 = w / 7;
    for (int pt = w; pt < 28; pt += 16) {
      const int mb = mt << 4;
      const int ntA = nt2 << 1;
      f32x4 accA = {0.f, 0.f, 0.f, 0.f};
      f32x4 accB = {0.f, 0.f, 0.f, 0.f};
#pragma unroll
      for (int kk = 0; kk < 4; ++kk) {
        bf16x8 a  = *(const bf16x8*)(Q + (mb + l15) * LD + kk * 32 + l4 * 8);
        bf16x8 b0 = *(const bf16x8*)(wproj + (((ntA << 2) + kk) * 64 + lane) * 8);
        bf16x8 b1 = *(const bf16x8*)(wproj + ((((ntA + 1) << 2) + kk) * 64 + lane) * 8);
        accA = __builtin_amdgcn_mfma_f32_16x16x32_bf16(a, b0, accA, 0, 0, 0);
        accB = __builtin_amdgcn_mfma_f32_16x16x32_bf16(a, b1, accB, 0, 0, 0);
      }
#pragma unroll
      for (int u = 0; u < 2; ++u) {
        f32x4 acc = u ? accB : accA;
        int n = ((ntA + u) << 4) + l15;
        float pb = proj_b[n];
#pragma unroll
        for (int j = 0; j < 4; ++j) {
          int i = mb + (l4 << 2) + j;
          if (i < NTOK) outw[i * CDIM + n] = acc[j] + pb;
        }
      }
      mt += 2; nt2 += 2;
      if (mt >= 7) { mt -= 7; ++nt2; }
    }
  }
}

extern "C" void kernel_launch(void* const* d_in, const int* in_sizes, int n_in,
                              void* d_out, int out_size, void* d_ws, size_t ws_size,
                              hipStream_t stream) {
  const float* x        = (const float*)d_in[0];
  const float* mask     = (const float*)d_in[1];
  const float* qkv_w    = (const float*)d_in[2];
  const float* qkv_b    = (const float*)d_in[3];
  const float* proj_w   = (const float*)d_in[4];
  const float* proj_b   = (const float*)d_in[5];
  const float* bias_tab = (const float*)d_in[6];
  const int*   rel_idx  = (const int*)d_in[7];
  float* out = (float*)d_out;

  __bf16* wqkv  = (__bf16*)d_ws;                        //  98304 B
  __bf16* wproj = (__bf16*)((char*)d_ws + 98304);       //  32768 B
  float*  combp = (float*)((char*)d_ws + 131072);       //  4*64*112*112*4 = 12845056 B

  precompute_k<<<1024, 256, 0, stream>>>(qkv_w, proj_w, bias_tab, rel_idx, mask, wqkv, wproj, combp);

  hipFuncSetAttribute(reinterpret_cast<const void*>(wattn_k),
                      hipFuncAttributeMaxDynamicSharedMemorySize, SM_TOTAL);
  wattn_k<<<4096, 1024, SM_TOTAL, stream>>>(x, qkv_b, proj_b, wqkv, wproj, combp, out);
}